// Round 19
// baseline (109.568 us; speedup 1.0000x reference)
//
#include <hip/hip_runtime.h>
#include <hip/hip_bf16.h>

// Capsule dynamic routing — TWO dispatches, CODE-SIZE-MINIMIZED serial kernel.
// r18 smoking gun: kf replays with FETCH=0.13MB (all cache-hit) still took
// 96us with all pipes <3% busy -> stall is instruction fetch, not data.
// Covariate across 18 rounds: slow kernels all have 30-80KB unrolled bodies;
// kd_mfma (same body, 16-rep loop) = 53us rep1 then 1.9us/rep warm -> I$.
// Fix: tt and it loops NOT unrolled (body appears once, ~3KB). Math is r18
// verbatim (hi-only phase2, proven absmax 0.0039).

#define BB 64
#define NN 2048
#define DD 64
#define II 32

typedef __attribute__((ext_vector_type(8)))  short bf16x8;
typedef __attribute__((ext_vector_type(16))) float f32x16;

__device__ __forceinline__ short f2bf(float f) {
    __hip_bfloat16 h = __float2bfloat16(f);
    return *reinterpret_cast<short*>(&h);
}

// ---------------- wide kernel: spart[cb][b][d] = sum of 64 rows ----------------
__global__ __launch_bounds__(256) void ksum(const float* __restrict__ u,
                                            float* __restrict__ spart) {
    int b = blockIdx.y, cb = blockIdx.x;        // cb: 0..31, 64 rows each
    int tid = threadIdx.x, cg = tid & 15, rr = tid >> 4;
    const float4* up = reinterpret_cast<const float4*>(
        u + ((size_t)b * NN + (size_t)cb * 64 + rr) * DD) + cg;
    float4 a = {0.f, 0.f, 0.f, 0.f};
    #pragma unroll
    for (int k = 0; k < 4; ++k) {
        float4 v = up[(size_t)k * 16 * (DD / 4)];
        a.x += v.x; a.y += v.y; a.z += v.z; a.w += v.w;
    }
    __shared__ float4 red[16][16];
    red[rr][cg] = a;
    __syncthreads();
    if (rr == 0) {
        float4 s = red[0][cg];
        #pragma unroll
        for (int r = 1; r < 16; ++r) {
            s.x += red[r][cg].x; s.y += red[r][cg].y;
            s.z += red[r][cg].z; s.w += red[r][cg].w;
        }
        reinterpret_cast<float4*>(spart + ((size_t)cb * BB + b) * DD)[cg] = s;
    }
}

// ---------------- fused kernel: 64 blocks x 512 threads, small code ----------
__global__ __launch_bounds__(512) void kf(const float* __restrict__ u,
                                          const float* __restrict__ W,
                                          const float* __restrict__ spart,
                                          float* __restrict__ out) {
    int b = blockIdx.x;
    int tid = threadIdx.x;
    int wv = tid >> 6;                  // wave 0..7, owns 256 rows
    int l = tid & 63, h = l >> 5, ln = l & 31;
    int ii = tid >> 4, jj0 = tid & 15;

    __shared__ unsigned short ush[8][2048];   // 32 KB per-wave u tile, bf16 hi
    __shared__ float cslab[8][II * 33];       // 33.8 KB per-wave c[n][i]
    __shared__ float tlds[II][65];            // 8.3 KB
    __shared__ float wlds[II][68];            // 8.7 KB
    __shared__ float ssum[DD];
    __shared__ float osh[II][16];

    const float* ubase = u + (size_t)b * NN * DD;

    // ---- phase B: s from spart, o0, l2norm, w~ ----
    if (tid < DD) {
        float a = 0.f;
        #pragma unroll 1
        for (int cb = 0; cb < 32; ++cb)
            a += spart[((size_t)cb * BB + b) * DD + tid];
        ssum[tid] = a;
    }
    for (int k = tid; k < II * 65; k += 512) (&tlds[0][0])[k] = 0.f;
    __syncthreads();
    {
        float o = 0.f;
        #pragma unroll 4
        for (int d = 0; d < DD; ++d) o += ssum[d] * W[d * 512 + ii * 16 + jj0];
        o *= (1.0f / 32.0f);
        float ss = o * o;
        #pragma unroll
        for (int off = 8; off >= 1; off >>= 1) ss += __shfl_xor(ss, off, 16);
        osh[ii][jj0] = o / sqrtf(fmaxf(ss, 1e-12f));
    }
    __syncthreads();
    #pragma unroll 1
    for (int k = 0; k < 4; ++k) {
        int d = jj0 + 16 * k;
        float acc = 0.f;
        #pragma unroll
        for (int j2 = 0; j2 < 16; ++j2)
            acc += W[d * 512 + ii * 16 + j2] * osh[ii][j2];
        wlds[ii][d] = acc;
    }
    __syncthreads();

    // ---- routing iterations (NOT unrolled: body appears once) ----
    #pragma unroll 1
    for (int it = 0; it < 2; ++it) {
        bf16x8 Aw[4];
        #pragma unroll
        for (int kt = 0; kt < 4; ++kt) {
            const float* p = &wlds[ln][kt * 16 + h * 8];
            #pragma unroll
            for (int e2 = 0; e2 < 8; ++e2) Aw[kt][e2] = f2bf(p[e2]);
        }
        f32x16 G0, G1;
        #pragma unroll
        for (int r = 0; r < 16; ++r) { G0[r] = 0.f; G1[r] = 0.f; }

        #pragma unroll 1
        for (int tt = 0; tt < 8; ++tt) {
            int n0 = wv * 256 + tt * 32;
            // load row n0+ln (8 float4), cvt hi-only, stage swizzled slab
            bf16x8 Bh[4];
            #pragma unroll
            for (int kt = 0; kt < 4; ++kt) {
                const float4* p = reinterpret_cast<const float4*>(
                    ubase + (size_t)(n0 + ln) * DD + kt * 16 + h * 8);
                float4 v0 = p[0], v1 = p[1];
                Bh[kt][0] = f2bf(v0.x); Bh[kt][1] = f2bf(v0.y);
                Bh[kt][2] = f2bf(v0.z); Bh[kt][3] = f2bf(v0.w);
                Bh[kt][4] = f2bf(v1.x); Bh[kt][5] = f2bf(v1.y);
                Bh[kt][6] = f2bf(v1.z); Bh[kt][7] = f2bf(v1.w);
                int d0 = kt * 16 + h * 8;
                int idx = ln * 64 + (d0 ^ ((ln & 7) << 3));
                *reinterpret_cast<bf16x8*>(&ush[wv][idx]) = Bh[kt];
            }
            // phase 1: logits C[i][n], col = ln
            f32x16 S;
            #pragma unroll
            for (int r = 0; r < 16; ++r) S[r] = 0.f;
            #pragma unroll
            for (int kt = 0; kt < 4; ++kt)
                S = __builtin_amdgcn_mfma_f32_32x32x16_bf16(Aw[kt], Bh[kt], S, 0, 0, 0);
            // softmax over i (16 lane-local + partner half via xor 32)
            float m = S[0];
            #pragma unroll
            for (int r = 1; r < 16; ++r) m = fmaxf(m, S[r]);
            m = fmaxf(m, __shfl_xor(m, 32));
            float sum = 0.f, e[16];
            #pragma unroll
            for (int r = 0; r < 16; ++r) { e[r] = __expf(S[r] - m); sum += e[r]; }
            sum += __shfl_xor(sum, 32);
            float inv = 1.f / sum;
            #pragma unroll
            for (int r = 0; r < 16; ++r) {
                int irow = (r & 3) + 8 * (r >> 2) + 4 * h;
                cslab[wv][ln * 33 + irow] = e[r] * inv;   // c[n=ln][i]
            }
            // phase 2: G += mfma(c^T, u), hi-only
            #pragma unroll
            for (int t2 = 0; t2 < 2; ++t2) {
                bf16x8 Ah;
                #pragma unroll
                for (int qq = 0; qq < 8; ++qq)
                    Ah[qq] = f2bf(cslab[wv][(t2 * 16 + h * 8 + qq) * 33 + ln]);
                #pragma unroll
                for (int Nt = 0; Nt < 2; ++Nt) {
                    bf16x8 B2h;
                    #pragma unroll
                    for (int qq = 0; qq < 8; ++qq) {
                        int row = t2 * 16 + h * 8 + qq;
                        int idx = row * 64 + ((Nt * 32 + ln) ^ ((row & 7) << 3));
                        B2h[qq] = (short)ush[wv][idx];
                    }
                    if (Nt == 0)
                        G0 = __builtin_amdgcn_mfma_f32_32x32x16_bf16(Ah, B2h, G0, 0, 0, 0);
                    else
                        G1 = __builtin_amdgcn_mfma_f32_32x32x16_bf16(Ah, B2h, G1, 0, 0, 0);
                }
            }
        }

        // cross-wave LDS reduce
        #pragma unroll
        for (int r = 0; r < 16; ++r) {
            int irow = (r & 3) + 8 * (r >> 2) + 4 * h;
            atomicAdd(&tlds[irow][ln],      G0[r]);
            atomicAdd(&tlds[irow][32 + ln], G1[r]);
        }
        __syncthreads();

        // epilogue: o = t @ W_i, l2norm->w~ or squash->out
        float o = 0.f;
        #pragma unroll 4
        for (int d = 0; d < DD; ++d) o += tlds[ii][d] * W[d * 512 + ii * 16 + jj0];
        float ss = o * o;
        #pragma unroll
        for (int off = 8; off >= 1; off >>= 1) ss += __shfl_xor(ss, off, 16);

        if (it == 0) {
            float ov = o / sqrtf(fmaxf(ss, 1e-12f));     // tf l2_normalize
            __syncthreads();
            osh[ii][jj0] = ov;
            __syncthreads();
            #pragma unroll 1
            for (int k = 0; k < 4; ++k) {
                int d = jj0 + 16 * k;
                float acc = 0.f;
                #pragma unroll
                for (int j2 = 0; j2 < 16; ++j2)
                    acc += W[d * 512 + ii * 16 + j2] * osh[ii][j2];
                wlds[ii][d] = acc;
            }
            for (int k = tid; k < II * 65; k += 512) (&tlds[0][0])[k] = 0.f;
            __syncthreads();
        } else {
            float s2 = ss + 1e-7f;                       // K.epsilon
            float scale = sqrtf(s2) / (0.5f + s2);       // squash
            out[(size_t)b * 512 + tid] = scale * o;
        }
    }
}

extern "C" void kernel_launch(void* const* d_in, const int* in_sizes, int n_in,
                              void* d_out, int out_size, void* d_ws, size_t ws_size,
                              hipStream_t stream) {
    const float* u = (const float*)d_in[0];     // (64, 2048, 64)
    const float* W = (const float*)d_in[1];     // (1, 64, 512)
    float* out = (float*)d_out;                 // (64, 32, 16)
    float* ws = (float*)d_ws;

    float* spart = ws;                          // 131072 floats (512 KB)

    ksum<<<dim3(32, BB), 256, 0, stream>>>(u, spart);   // wide: all CUs
    kf<<<BB, 512, 0, stream>>>(u, W, spart, out);       // fused routing
}

// Round 20
// 100.665 us; speedup vs baseline: 1.0884x; 1.0884x over previous
//
#include <hip/hip_runtime.h>
#include <hip/hip_bf16.h>

// Capsule dynamic routing — FINAL (r18 configuration, best measured: 100.6us).
//   ksum (wide, 2048 wg): spart = per-64-row sums of u (all CUs, ~4us)
//   kf   (64 x 512):      fused routing, minimal serial work (~96us)
// Session findings (r3-r19): a ~55-60us per-serial-pass cost invisible to all
// PMC busy counters, invariant to 8 distinct structural mechanisms (LDS size,
// atomics, access patterns, gload_lds, occupancy, cross-block sync [~100us/
// barrier on this 8-XCD part], dirty-line fan-out, MLP/prefetch, code size);
// amortizes only in rep-loops on wide grids (kd_mfma: 3.2TB/s steady-state).
// Best structure: ONE serial pass per routing iteration, everything else wide.
// Math: factored routing (no 268MB u_hat), MFMA 32x32x16 bf16, swapped phase1
// (softmax lane-local, 2 shuffles), hi-only bf16 phase2. absmax 0.0039 << 1.77e-2.

#define BB 64
#define NN 2048
#define DD 64
#define II 32

typedef __attribute__((ext_vector_type(8)))  short bf16x8;
typedef __attribute__((ext_vector_type(16))) float f32x16;

__device__ __forceinline__ short f2bf(float f) {
    __hip_bfloat16 h = __float2bfloat16(f);
    return *reinterpret_cast<short*>(&h);
}

// ---------------- wide kernel: spart[cb][b][d] = sum of 64 rows ----------------
__global__ __launch_bounds__(256) void ksum(const float* __restrict__ u,
                                            float* __restrict__ spart) {
    int b = blockIdx.y, cb = blockIdx.x;        // cb: 0..31, 64 rows each
    int tid = threadIdx.x, cg = tid & 15, rr = tid >> 4;
    const float4* up = reinterpret_cast<const float4*>(
        u + ((size_t)b * NN + (size_t)cb * 64 + rr) * DD) + cg;
    float4 a = {0.f, 0.f, 0.f, 0.f};
    #pragma unroll
    for (int k = 0; k < 4; ++k) {
        float4 v = up[(size_t)k * 16 * (DD / 4)];
        a.x += v.x; a.y += v.y; a.z += v.z; a.w += v.w;
    }
    __shared__ float4 red[16][16];
    red[rr][cg] = a;
    __syncthreads();
    if (rr == 0) {
        float4 s = red[0][cg];
        #pragma unroll
        for (int r = 1; r < 16; ++r) {
            s.x += red[r][cg].x; s.y += red[r][cg].y;
            s.z += red[r][cg].z; s.w += red[r][cg].w;
        }
        reinterpret_cast<float4*>(spart + ((size_t)cb * BB + b) * DD)[cg] = s;
    }
}

// ---------------- fused kernel: 64 blocks x 512 threads ----------------
__global__ __launch_bounds__(512) void kf(const float* __restrict__ u,
                                          const float* __restrict__ W,
                                          const float* __restrict__ spart,
                                          float* __restrict__ out) {
    int b = blockIdx.x;
    int tid = threadIdx.x;
    int wv = tid >> 6;                  // wave 0..7, owns 256 rows
    int l = tid & 63, h = l >> 5, ln = l & 31;
    int ii = tid >> 4, jj0 = tid & 15;

    __shared__ unsigned short ush[8][2048];   // 32 KB per-wave u tile, bf16 hi
    __shared__ float cslab[8][II * 33];       // 33.8 KB per-wave c[n][i]
    __shared__ float tlds[II][65];            // 8.3 KB
    __shared__ float wlds[II][68];            // 8.7 KB
    __shared__ float ssum[DD];
    __shared__ float osh[II][16];

    const float* ubase = u + (size_t)b * NN * DD;

    // ---- phase B: s from spart, o0, l2norm, w~ ----
    if (tid < DD) {
        float a = 0.f;
        #pragma unroll
        for (int cb = 0; cb < 32; ++cb)
            a += spart[((size_t)cb * BB + b) * DD + tid];
        ssum[tid] = a;
    }
    for (int k = tid; k < II * 65; k += 512) (&tlds[0][0])[k] = 0.f;
    __syncthreads();
    {
        float o = 0.f;
        #pragma unroll 8
        for (int d = 0; d < DD; ++d) o += ssum[d] * W[d * 512 + ii * 16 + jj0];
        o *= (1.0f / 32.0f);
        float ss = o * o;
        #pragma unroll
        for (int off = 8; off >= 1; off >>= 1) ss += __shfl_xor(ss, off, 16);
        osh[ii][jj0] = o / sqrtf(fmaxf(ss, 1e-12f));
    }
    __syncthreads();
    #pragma unroll
    for (int k = 0; k < 4; ++k) {
        int d = jj0 + 16 * k;
        float acc = 0.f;
        #pragma unroll
        for (int j2 = 0; j2 < 16; ++j2)
            acc += W[d * 512 + ii * 16 + j2] * osh[ii][j2];
        wlds[ii][d] = acc;
    }
    __syncthreads();

    // ---- routing iterations ----
    for (int it = 0; it < 2; ++it) {
        bf16x8 Aw[4];
        #pragma unroll
        for (int kt = 0; kt < 4; ++kt) {
            const float* p = &wlds[ln][kt * 16 + h * 8];
            #pragma unroll
            for (int e2 = 0; e2 < 8; ++e2) Aw[kt][e2] = f2bf(p[e2]);
        }
        f32x16 G0, G1;
        #pragma unroll
        for (int r = 0; r < 16; ++r) { G0[r] = 0.f; G1[r] = 0.f; }

        for (int tt = 0; tt < 8; ++tt) {
            int n0 = wv * 256 + tt * 32;
            // load row n0+ln (8 float4), cvt hi-only, stage swizzled slab
            bf16x8 Bh[4];
            #pragma unroll
            for (int kt = 0; kt < 4; ++kt) {
                const float4* p = reinterpret_cast<const float4*>(
                    ubase + (size_t)(n0 + ln) * DD + kt * 16 + h * 8);
                float4 v0 = p[0], v1 = p[1];
                Bh[kt][0] = f2bf(v0.x); Bh[kt][1] = f2bf(v0.y);
                Bh[kt][2] = f2bf(v0.z); Bh[kt][3] = f2bf(v0.w);
                Bh[kt][4] = f2bf(v1.x); Bh[kt][5] = f2bf(v1.y);
                Bh[kt][6] = f2bf(v1.z); Bh[kt][7] = f2bf(v1.w);
                int d0 = kt * 16 + h * 8;
                int idx = ln * 64 + (d0 ^ ((ln & 7) << 3));
                *reinterpret_cast<bf16x8*>(&ush[wv][idx]) = Bh[kt];
            }
            // phase 1: logits C[i][n], col = ln  -> cheap lane-local softmax
            f32x16 S;
            #pragma unroll
            for (int r = 0; r < 16; ++r) S[r] = 0.f;
            #pragma unroll
            for (int kt = 0; kt < 4; ++kt)
                S = __builtin_amdgcn_mfma_f32_32x32x16_bf16(Aw[kt], Bh[kt], S, 0, 0, 0);
            float m = S[0];
            #pragma unroll
            for (int r = 1; r < 16; ++r) m = fmaxf(m, S[r]);
            m = fmaxf(m, __shfl_xor(m, 32));
            float sum = 0.f, e[16];
            #pragma unroll
            for (int r = 0; r < 16; ++r) { e[r] = __expf(S[r] - m); sum += e[r]; }
            sum += __shfl_xor(sum, 32);
            float inv = 1.f / sum;
            #pragma unroll
            for (int r = 0; r < 16; ++r) {
                int irow = (r & 3) + 8 * (r >> 2) + 4 * h;
                cslab[wv][ln * 33 + irow] = e[r] * inv;   // c[n=ln][i]
            }
            // phase 2: G += mfma(c^T, u), hi-only (4 MFMA/tile)
            #pragma unroll
            for (int t2 = 0; t2 < 2; ++t2) {
                bf16x8 Ah;
                #pragma unroll
                for (int qq = 0; qq < 8; ++qq)
                    Ah[qq] = f2bf(cslab[wv][(t2 * 16 + h * 8 + qq) * 33 + ln]);
                #pragma unroll
                for (int Nt = 0; Nt < 2; ++Nt) {
                    bf16x8 B2h;
                    #pragma unroll
                    for (int qq = 0; qq < 8; ++qq) {
                        int row = t2 * 16 + h * 8 + qq;
                        int idx = row * 64 + ((Nt * 32 + ln) ^ ((row & 7) << 3));
                        B2h[qq] = (short)ush[wv][idx];
                    }
                    if (Nt == 0)
                        G0 = __builtin_amdgcn_mfma_f32_32x32x16_bf16(Ah, B2h, G0, 0, 0, 0);
                    else
                        G1 = __builtin_amdgcn_mfma_f32_32x32x16_bf16(Ah, B2h, G1, 0, 0, 0);
                }
            }
        }

        // cross-wave LDS reduce
        #pragma unroll
        for (int r = 0; r < 16; ++r) {
            int irow = (r & 3) + 8 * (r >> 2) + 4 * h;
            atomicAdd(&tlds[irow][ln],      G0[r]);
            atomicAdd(&tlds[irow][32 + ln], G1[r]);
        }
        __syncthreads();

        // epilogue: o = t @ W_i, l2norm->w~ or squash->out
        float o = 0.f;
        #pragma unroll 8
        for (int d = 0; d < DD; ++d) o += tlds[ii][d] * W[d * 512 + ii * 16 + jj0];
        float ss = o * o;
        #pragma unroll
        for (int off = 8; off >= 1; off >>= 1) ss += __shfl_xor(ss, off, 16);

        if (it == 0) {
            float ov = o / sqrtf(fmaxf(ss, 1e-12f));     // tf l2_normalize
            __syncthreads();
            osh[ii][jj0] = ov;
            __syncthreads();
            #pragma unroll
            for (int k = 0; k < 4; ++k) {
                int d = jj0 + 16 * k;
                float acc = 0.f;
                #pragma unroll
                for (int j2 = 0; j2 < 16; ++j2)
                    acc += W[d * 512 + ii * 16 + j2] * osh[ii][j2];
                wlds[ii][d] = acc;
            }
            for (int k = tid; k < II * 65; k += 512) (&tlds[0][0])[k] = 0.f;
            __syncthreads();
        } else {
            float s2 = ss + 1e-7f;                       // K.epsilon
            float scale = sqrtf(s2) / (0.5f + s2);       // squash
            out[(size_t)b * 512 + tid] = scale * o;
        }
    }
}

extern "C" void kernel_launch(void* const* d_in, const int* in_sizes, int n_in,
                              void* d_out, int out_size, void* d_ws, size_t ws_size,
                              hipStream_t stream) {
    const float* u = (const float*)d_in[0];     // (64, 2048, 64)
    const float* W = (const float*)d_in[1];     // (1, 64, 512)
    float* out = (float*)d_out;                 // (64, 32, 16)
    float* ws = (float*)d_ws;

    float* spart = ws;                          // 131072 floats (512 KB)

    ksum<<<dim3(32, BB), 256, 0, stream>>>(u, spart);   // wide: all CUs
    kf<<<BB, 512, 0, stream>>>(u, W, spart, out);       // fused routing
}